// Round 5
// baseline (1604298.438 us; speedup 1.0000x reference)
//
#include <hip/hip_runtime.h>
#include <math.h>

#define T_STEPS 65536
#define HID     512
#define NACT    64     // cohort size (all on one XCD, runtime-verified)
#define NLAUNCH 512    // launched WGs; pigeonhole => some XCD gets >= 64
#define WGSIZE  256

typedef unsigned int uint4v __attribute__((ext_vector_type(4)));
typedef float        f4v   __attribute__((ext_vector_type(4)));

// 16B poll, L2-level: bypass L1 (sc0), hit the XCD-shared L2.
// "=&v" early-clobber is REQUIRED: dest must not overlap the addr pair
// (missing it caused the R4 infinite-poll hang).
__device__ __forceinline__ uint4v poll16_l2(const unsigned long long* p) {
  uint4v v;
  asm volatile("global_load_dwordx4 %0, %1, off sc0\n\t"
               "s_waitcnt vmcnt(0)"
               : "=&v"(v) : "v"(p) : "memory");
  return v;
}
// LIC-level fallback poll (sc0 sc1): known-good from R2. Used 1/256 spins as
// liveness insurance — if L2 visibility assumption fails we degrade, not hang.
__device__ __forceinline__ uint4v poll16_lic(const unsigned long long* p) {
  uint4v v;
  asm volatile("global_load_dwordx4 %0, %1, off sc0 sc1\n\t"
               "s_waitcnt vmcnt(0)"
               : "=&v"(v) : "v"(p) : "memory");
  return v;
}

// Layout per active WG (256 thr = 4 waves):
//   cohort slot owns 8 h-indices: [slot*8, slot*8+8).
//   Wave wid owns 2 h-indices; lane = r + 8*g: r->(jloc=r&1, gate=r>>1), g = k-group.
//   Each lane holds 64 fp32 of W_hh and W_ih (registers).
// Exchange: hbuf[2][512] packed (hi32 = tag = t+1, lo32 = h bits) in the winner
// XCD's L2: plain stores (write-through vL1 -> local L2) + sc0 polls.
// 1 barrier/step via double-buffered LDS.

__global__ __launch_bounds__(WGSIZE, 1)
void lstm_persistent(const float* __restrict__ x,      // [T,512]
                     const float* __restrict__ Wih,    // [2048,512]
                     const float* __restrict__ Whh,    // [2048,512]
                     const float* __restrict__ bih,    // [2048]
                     const float* __restrict__ bhh,    // [2048]
                     float* __restrict__ out,          // [512]
                     unsigned long long* hbuf,         // [2][512] tagged pairs
                     int* elect)                       // [8] counters + [1] winner
{
  const int tid = threadIdx.x;

  // ---- XCD cohort election (one-time, agent-scope; placement verified) ----
  __shared__ int s_slot;
  if (tid == 0) {
    int xcd;
    asm volatile("s_getreg_b32 %0, hwreg(HW_REG_XCC_ID)" : "=s"(xcd));
    int slot = __hip_atomic_fetch_add(&elect[xcd], 1, __ATOMIC_RELAXED,
                                      __HIP_MEMORY_SCOPE_AGENT);
    if (slot == NACT - 1) {   // my XCD just filled a full cohort: try to win
      int exp0 = 0;
      __hip_atomic_compare_exchange_strong(&elect[8], &exp0, xcd + 1,
          __ATOMIC_RELEASE, __ATOMIC_RELAXED, __HIP_MEMORY_SCOPE_AGENT);
    }
    int w;
    do {
      w = __hip_atomic_load(&elect[8], __ATOMIC_ACQUIRE, __HIP_MEMORY_SCOPE_AGENT);
      if (w == 0) __builtin_amdgcn_s_sleep(2);
    } while (w == 0);
    s_slot = (xcd == w - 1 && slot < NACT) ? slot : -1;
  }
  __syncthreads();
  const int slot = s_slot;
  if (slot < 0) return;   // not in the winning cohort

  const int wid  = tid >> 6;
  const int lane = tid & 63;
  const int r    = lane & 7;
  const int g    = lane >> 3;
  const int k0   = g << 6;            // 64-float k-slice start
  const int jloc = r & 1;
  const int gate = r >> 1;            // 0=i 1=f 2=g 3=o
  const int hidx = slot * 8 + wid * 2 + jloc;
  const int row  = gate * HID + hidx;

  __shared__ __align__(16) float hl[2][512];
  __shared__ __align__(16) float xl[2][512];

  // ---- load weights into registers (static indices only) ----
  float whh[64], wih[64];
#pragma unroll
  for (int i = 0; i < 16; ++i) {
    const int kk = k0 + (((i + g) & 15) << 2);
    float4 a = *reinterpret_cast<const float4*>(Whh + (size_t)row * 512 + kk);
    float4 b = *reinterpret_cast<const float4*>(Wih + (size_t)row * 512 + kk);
    whh[4*i+0] = a.x; whh[4*i+1] = a.y; whh[4*i+2] = a.z; whh[4*i+3] = a.w;
    wih[4*i+0] = b.x; wih[4*i+1] = b.y; wih[4*i+2] = b.z; wih[4*i+3] = b.w;
  }
  const float bias = bih[row] + bhh[row];

  // ---- stage x_0 ----
  if (tid < 128) {
    float4 v = reinterpret_cast<const float4*>(x)[tid];
    *reinterpret_cast<float4*>(&xl[0][tid * 4]) = v;
  }
  __syncthreads();

  auto dot_lds = [&](const float* lds, const float* w) -> float {
    float acc = 0.f;
#pragma unroll
    for (int i = 0; i < 16; ++i) {
      const int kk = k0 + (((i + g) & 15) << 2);
      float4 v = *reinterpret_cast<const float4*>(lds + kk);
      acc = fmaf(w[4*i+0], v.x, acc);
      acc = fmaf(w[4*i+1], v.y, acc);
      acc = fmaf(w[4*i+2], v.z, acc);
      acc = fmaf(w[4*i+3], v.w, acc);
    }
    return acc;
  };

  float xacc = dot_lds(xl[0], wih);   // x-projection partial for t=0
  float c    = 0.f;

#pragma unroll 1
  for (int t = 0; t < T_STEPS; ++t) {
    // ---- stage: x_{t+1} (nontemporal, don't pollute L2) + poll h_{t-1} ----
    f4v xv;
    const bool do_x = (tid < 128) && (t + 1 < T_STEPS);
    if (do_x) {
      const f4v* xp = reinterpret_cast<const f4v*>(x + (size_t)(t + 1) * 512) + tid;
      xv = __builtin_nontemporal_load(xp);
    }
    if (t > 0) {
      const unsigned long long* src = hbuf + (((t - 1) & 1) << 9) + (tid << 1);
      const unsigned exp = (unsigned)t;
      uint4v p;
      int spins = 0;
      while (true) {
        p = ((++spins & 255) != 0) ? poll16_l2(src) : poll16_lic(src);
        if (p.y == exp && p.w == exp) break;
      }
      hl[t & 1][(tid << 1) + 0] = __uint_as_float(p.x);
      hl[t & 1][(tid << 1) + 1] = __uint_as_float(p.z);
    }
    if (do_x) *reinterpret_cast<f4v*>(&xl[(t + 1) & 1][tid * 4]) = xv;
    __syncthreads();   // single barrier per step (LDS double-buffered)

    // ---- gate pre-activation: xacc + h-dot, reduce over 8 k-groups ----
    float acc = xacc;
    if (t > 0) acc += dot_lds(hl[t & 1], whh);
    acc += __shfl_xor(acc, 8);
    acc += __shfl_xor(acc, 16);
    acc += __shfl_xor(acc, 32);
    acc += bias;

    // ---- nonlinearity: sigmoid for i,f,o; tanh (=2*sig(2x)-1) for g ----
    const bool isg = (gate == 2);
    float xs = isg ? 2.f * acc : acc;
    float s  = 1.f / (1.f + expf(-xs));
    float v  = isg ? (2.f * s - 1.f) : s;

    // ---- gather i,f,g,o for my jloc via in-wave shuffles ----
    float iv = __shfl(v, jloc + 0);
    float fv = __shfl(v, jloc + 2);
    float gv = __shfl(v, jloc + 4);
    float ov = __shfl(v, jloc + 6);

    c = fv * c + iv * gv;
    float e2 = expf(-2.f * c);
    float th = 2.f / (1.f + e2) - 1.f;
    float hn = ov * th;

    // ---- post tagged h_t: plain 8B store -> write-through vL1 -> local L2.
    // (poll asm memory clobbers fence elision/reordering; aligned 8B is untorn)
    if (lane < 2) {
      unsigned long long pk =
          ((unsigned long long)(unsigned)(t + 1) << 32) | (unsigned)__float_as_uint(hn);
      hbuf[((t & 1) << 9) + slot * 8 + wid * 2 + lane] = pk;
    }

    // ---- overlap: x-projection partial for step t+1 (hides peers' latency) ----
    if (t + 1 < T_STEPS) xacc = dot_lds(xl[(t + 1) & 1], wih);
  }

  // ---- softmax(h_{T-1}) by cohort slot 0, wave 0 ----
  if (slot == 0 && wid == 0) {
    const unsigned long long* src = hbuf + (((T_STEPS - 1) & 1) << 9) + lane * 8;
    float hv[8];
#pragma unroll
    for (int pr = 0; pr < 4; ++pr) {
      uint4v p;
      int spins = 0;
      while (true) {
        p = ((++spins & 255) != 0) ? poll16_l2(src + pr * 2) : poll16_lic(src + pr * 2);
        if (p.y == (unsigned)T_STEPS && p.w == (unsigned)T_STEPS) break;
      }
      hv[pr * 2 + 0] = __uint_as_float(p.x);
      hv[pr * 2 + 1] = __uint_as_float(p.z);
    }
    float mx = hv[0];
#pragma unroll
    for (int m2 = 1; m2 < 8; ++m2) mx = fmaxf(mx, hv[m2]);
    mx = fmaxf(mx, __shfl_xor(mx, 1));
    mx = fmaxf(mx, __shfl_xor(mx, 2));
    mx = fmaxf(mx, __shfl_xor(mx, 4));
    mx = fmaxf(mx, __shfl_xor(mx, 8));
    mx = fmaxf(mx, __shfl_xor(mx, 16));
    mx = fmaxf(mx, __shfl_xor(mx, 32));
    float ex[8], sum = 0.f;
#pragma unroll
    for (int m2 = 0; m2 < 8; ++m2) { ex[m2] = expf(hv[m2] - mx); sum += ex[m2]; }
    sum += __shfl_xor(sum, 1);
    sum += __shfl_xor(sum, 2);
    sum += __shfl_xor(sum, 4);
    sum += __shfl_xor(sum, 8);
    sum += __shfl_xor(sum, 16);
    sum += __shfl_xor(sum, 32);
    float inv = 1.f / sum;
#pragma unroll
    for (int m2 = 0; m2 < 8; ++m2) out[lane * 8 + m2] = ex[m2] * inv;
  }
}

extern "C" void kernel_launch(void* const* d_in, const int* in_sizes, int n_in,
                              void* d_out, int out_size, void* d_ws, size_t ws_size,
                              hipStream_t stream) {
  const float* x   = (const float*)d_in[0];
  const float* Wih = (const float*)d_in[1];
  const float* Whh = (const float*)d_in[2];
  const float* bih = (const float*)d_in[3];
  const float* bhh = (const float*)d_in[4];
  float* out = (float*)d_out;
  unsigned long long* hbuf = (unsigned long long*)d_ws;   // 2*512*8B = 8 KB
  int* elect = (int*)((char*)d_ws + 8192);                // 8 ctrs + winner

  (void)hipMemsetAsync(d_ws, 0, 8192 + 64, stream);  // zero tags+election (capture-safe)
  lstm_persistent<<<NLAUNCH, WGSIZE, 0, stream>>>(x, Wih, Whh, bih, bhh, out,
                                                  hbuf, elect);
}

// Round 6
// 376549.438 us; speedup vs baseline: 4.2605x; 4.2605x over previous
//
#include <hip/hip_runtime.h>
#include <math.h>

#define T_STEPS 65536
#define HID     512
#define NACT    64     // cohort size (all on one XCD, runtime-verified)
#define NLAUNCH 512    // launched WGs; pigeonhole => some XCD gets >= 64
#define WGSIZE  256

typedef unsigned int uint4v __attribute__((ext_vector_type(4)));
typedef float        f4v   __attribute__((ext_vector_type(4)));

// 16B poll, L2-level: bypass L1 (sc0), hit the XCD-shared L2.
// "=&v" early-clobber REQUIRED (missing it caused the R4 infinite-poll hang).
__device__ __forceinline__ uint4v poll16_l2(const unsigned long long* p) {
  uint4v v;
  asm volatile("global_load_dwordx4 %0, %1, off sc0\n\t"
               "s_waitcnt vmcnt(0)"
               : "=&v"(v) : "v"(p) : "memory");
  return v;
}
// LIC-level poll (sc0 sc1): known-good visibility from R2's agent atomics.
__device__ __forceinline__ uint4v poll16_lic(const unsigned long long* p) {
  uint4v v;
  asm volatile("global_load_dwordx4 %0, %1, off sc0 sc1\n\t"
               "s_waitcnt vmcnt(0)"
               : "=&v"(v) : "v"(p) : "memory");
  return v;
}
// Dual-post: sc0 (write-through to XCD L2, fast path) + sc0 sc1 (device/LIC,
// guaranteed path). Plain stores proved non-visible for ~24us in R5 (stuck in
// a CU-side write-back structure); explicit cache policy forces them out.
// Identical data both stores => any HW ordering/invalidation still leaves
// fresh data wherever each poll flavor looks. Fire-and-forget.
__device__ __forceinline__ void post8(unsigned long long* p, unsigned long long v) {
  asm volatile("global_store_dwordx2 %0, %1, off sc0\n\t"
               "global_store_dwordx2 %0, %1, off sc0 sc1"
               :: "v"(p), "v"(v) : "memory");
}

// Layout per active WG (256 thr = 4 waves):
//   cohort slot owns 8 h-indices: [slot*8, slot*8+8).
//   Wave wid owns 2 h-indices; lane = r + 8*g: r->(jloc=r&1, gate=r>>1), g = k-group.
//   Each lane holds 64 fp32 of W_hh and W_ih (registers/AGPRs).
// Exchange: hbuf[2][512] packed (hi32 = tag = t+1, lo32 = h bits).
// 1 barrier/step via double-buffered LDS.

__global__ __launch_bounds__(WGSIZE, 1)
void lstm_persistent(const float* __restrict__ x,      // [T,512]
                     const float* __restrict__ Wih,    // [2048,512]
                     const float* __restrict__ Whh,    // [2048,512]
                     const float* __restrict__ bih,    // [2048]
                     const float* __restrict__ bhh,    // [2048]
                     float* __restrict__ out,          // [512]
                     unsigned long long* hbuf,         // [2][512] tagged pairs
                     int* elect)                       // [8] counters + [1] winner
{
  const int tid = threadIdx.x;

  // ---- XCD cohort election (one-time, agent-scope; placement verified) ----
  __shared__ int s_slot;
  if (tid == 0) {
    int xcd;
    asm volatile("s_getreg_b32 %0, hwreg(HW_REG_XCC_ID)" : "=s"(xcd));
    int slot = __hip_atomic_fetch_add(&elect[xcd], 1, __ATOMIC_RELAXED,
                                      __HIP_MEMORY_SCOPE_AGENT);
    if (slot == NACT - 1) {   // my XCD just filled a full cohort: try to win
      int exp0 = 0;
      __hip_atomic_compare_exchange_strong(&elect[8], &exp0, xcd + 1,
          __ATOMIC_RELEASE, __ATOMIC_RELAXED, __HIP_MEMORY_SCOPE_AGENT);
    }
    int w;
    do {
      w = __hip_atomic_load(&elect[8], __ATOMIC_ACQUIRE, __HIP_MEMORY_SCOPE_AGENT);
      if (w == 0) __builtin_amdgcn_s_sleep(2);
    } while (w == 0);
    s_slot = (xcd == w - 1 && slot < NACT) ? slot : -1;
  }
  __syncthreads();
  const int slot = s_slot;
  if (slot < 0) return;   // not in the winning cohort

  const int wid  = tid >> 6;
  const int lane = tid & 63;
  const int r    = lane & 7;
  const int g    = lane >> 3;
  const int k0   = g << 6;            // 64-float k-slice start
  const int jloc = r & 1;
  const int gate = r >> 1;            // 0=i 1=f 2=g 3=o
  const int hidx = slot * 8 + wid * 2 + jloc;
  const int row  = gate * HID + hidx;

  __shared__ __align__(16) float hl[2][512];
  __shared__ __align__(16) float xl[2][512];

  // ---- load weights into registers (static indices only) ----
  float whh[64], wih[64];
#pragma unroll
  for (int i = 0; i < 16; ++i) {
    const int kk = k0 + (((i + g) & 15) << 2);
    float4 a = *reinterpret_cast<const float4*>(Whh + (size_t)row * 512 + kk);
    float4 b = *reinterpret_cast<const float4*>(Wih + (size_t)row * 512 + kk);
    whh[4*i+0] = a.x; whh[4*i+1] = a.y; whh[4*i+2] = a.z; whh[4*i+3] = a.w;
    wih[4*i+0] = b.x; wih[4*i+1] = b.y; wih[4*i+2] = b.z; wih[4*i+3] = b.w;
  }
  const float bias = bih[row] + bhh[row];

  // ---- stage x_0 ----
  if (tid < 128) {
    float4 v = reinterpret_cast<const float4*>(x)[tid];
    *reinterpret_cast<float4*>(&xl[0][tid * 4]) = v;
  }
  __syncthreads();

  // 4 rotating accumulators: FMA dep-chain 16 deep instead of 64.
  auto dot_lds = [&](const float* lds, const float* w) -> float {
    float a0 = 0.f, a1 = 0.f, a2 = 0.f, a3 = 0.f;
#pragma unroll
    for (int i = 0; i < 16; i += 4) {
#pragma unroll
      for (int j = 0; j < 4; ++j) {
        const int idx = i + j;
        const int kk = k0 + (((idx + g) & 15) << 2);
        float4 v = *reinterpret_cast<const float4*>(lds + kk);
        float t0 = fmaf(w[4*idx+0], v.x, fmaf(w[4*idx+1], v.y, 0.f));
        float t1 = fmaf(w[4*idx+2], v.z, fmaf(w[4*idx+3], v.w, 0.f));
        if (j == 0) a0 += t0 + t1;
        else if (j == 1) a1 += t0 + t1;
        else if (j == 2) a2 += t0 + t1;
        else a3 += t0 + t1;
      }
    }
    return (a0 + a1) + (a2 + a3);
  };

  float xacc = dot_lds(xl[0], wih);   // x-projection partial for t=0
  float c    = 0.f;

#pragma unroll 1
  for (int t = 0; t < T_STEPS; ++t) {
    // ---- stage: x_{t+1} (nontemporal) + poll h_{t-1} ----
    f4v xv;
    const bool do_x = (tid < 128) && (t + 1 < T_STEPS);
    if (do_x) {
      const f4v* xp = reinterpret_cast<const f4v*>(x + (size_t)(t + 1) * 512) + tid;
      xv = __builtin_nontemporal_load(xp);
    }
    if (t > 0) {
      const unsigned long long* src = hbuf + (((t - 1) & 1) << 9) + (tid << 1);
      const unsigned exp = (unsigned)t;
      uint4v p;
      int spins = 0;
      while (true) {
        p = ((++spins & 7) != 0) ? poll16_l2(src) : poll16_lic(src);
        if (p.y == exp && p.w == exp) break;
      }
      hl[t & 1][(tid << 1) + 0] = __uint_as_float(p.x);
      hl[t & 1][(tid << 1) + 1] = __uint_as_float(p.z);
    }
    if (do_x) *reinterpret_cast<f4v*>(&xl[(t + 1) & 1][tid * 4]) = xv;
    __syncthreads();   // single barrier per step (LDS double-buffered)

    // ---- gate pre-activation: xacc + h-dot, reduce over 8 k-groups ----
    float acc = xacc;
    if (t > 0) acc += dot_lds(hl[t & 1], whh);
    acc += __shfl_xor(acc, 8);
    acc += __shfl_xor(acc, 16);
    acc += __shfl_xor(acc, 32);
    acc += bias;

    // ---- nonlinearity: sigmoid for i,f,o; tanh (=2*sig(2x)-1) for g ----
    const bool isg = (gate == 2);
    float xs = isg ? 2.f * acc : acc;
    float s  = 1.f / (1.f + expf(-xs));
    float v  = isg ? (2.f * s - 1.f) : s;

    // ---- gather i,f,g,o for my jloc via in-wave shuffles ----
    float iv = __shfl(v, jloc + 0);
    float fv = __shfl(v, jloc + 2);
    float gv = __shfl(v, jloc + 4);
    float ov = __shfl(v, jloc + 6);

    c = fv * c + iv * gv;
    float e2 = expf(-2.f * c);
    float th = 2.f / (1.f + e2) - 1.f;
    float hn = ov * th;

    // ---- post tagged h_t (lanes 0,1 of every wave): dual-policy stores ----
    if (lane < 2) {
      unsigned long long pk =
          ((unsigned long long)(unsigned)(t + 1) << 32) | (unsigned)__float_as_uint(hn);
      post8(hbuf + ((t & 1) << 9) + slot * 8 + wid * 2 + lane, pk);
    }

    // ---- overlap: x-projection partial for step t+1 (hides peers' latency) ----
    if (t + 1 < T_STEPS) xacc = dot_lds(xl[(t + 1) & 1], wih);
  }

  // ---- softmax(h_{T-1}) by cohort slot 0, wave 0 ----
  if (slot == 0 && wid == 0) {
    const unsigned long long* src = hbuf + (((T_STEPS - 1) & 1) << 9) + lane * 8;
    float hv[8];
#pragma unroll
    for (int pr = 0; pr < 4; ++pr) {
      uint4v p;
      int spins = 0;
      while (true) {
        p = ((++spins & 7) != 0) ? poll16_l2(src + pr * 2) : poll16_lic(src + pr * 2);
        if (p.y == (unsigned)T_STEPS && p.w == (unsigned)T_STEPS) break;
      }
      hv[pr * 2 + 0] = __uint_as_float(p.x);
      hv[pr * 2 + 1] = __uint_as_float(p.z);
    }
    float mx = hv[0];
#pragma unroll
    for (int m2 = 1; m2 < 8; ++m2) mx = fmaxf(mx, hv[m2]);
    mx = fmaxf(mx, __shfl_xor(mx, 1));
    mx = fmaxf(mx, __shfl_xor(mx, 2));
    mx = fmaxf(mx, __shfl_xor(mx, 4));
    mx = fmaxf(mx, __shfl_xor(mx, 8));
    mx = fmaxf(mx, __shfl_xor(mx, 16));
    mx = fmaxf(mx, __shfl_xor(mx, 32));
    float ex[8], sum = 0.f;
#pragma unroll
    for (int m2 = 0; m2 < 8; ++m2) { ex[m2] = expf(hv[m2] - mx); sum += ex[m2]; }
    sum += __shfl_xor(sum, 1);
    sum += __shfl_xor(sum, 2);
    sum += __shfl_xor(sum, 4);
    sum += __shfl_xor(sum, 8);
    sum += __shfl_xor(sum, 16);
    sum += __shfl_xor(sum, 32);
    float inv = 1.f / sum;
#pragma unroll
    for (int m2 = 0; m2 < 8; ++m2) out[lane * 8 + m2] = ex[m2] * inv;
  }
}

extern "C" void kernel_launch(void* const* d_in, const int* in_sizes, int n_in,
                              void* d_out, int out_size, void* d_ws, size_t ws_size,
                              hipStream_t stream) {
  const float* x   = (const float*)d_in[0];
  const float* Wih = (const float*)d_in[1];
  const float* Whh = (const float*)d_in[2];
  const float* bih = (const float*)d_in[3];
  const float* bhh = (const float*)d_in[4];
  float* out = (float*)d_out;
  unsigned long long* hbuf = (unsigned long long*)d_ws;   // 2*512*8B = 8 KB
  int* elect = (int*)((char*)d_ws + 8192);                // 8 ctrs + winner

  (void)hipMemsetAsync(d_ws, 0, 8192 + 64, stream);  // zero tags+election (capture-safe)
  lstm_persistent<<<NLAUNCH, WGSIZE, 0, stream>>>(x, Wih, Whh, bih, bhh, out,
                                                  hbuf, elect);
}

// Round 7
// 145135.608 us; speedup vs baseline: 11.0538x; 2.5945x over previous
//
#include <hip/hip_runtime.h>
#include <math.h>

#define T_STEPS 65536
#define HID     512
#define NWG     256    // one wave per WG; wave w owns h-indices {2w, 2w+1}
#define WGSIZE  64

typedef float f4v __attribute__((ext_vector_type(4)));

// Per-wave layout: lane = r + 8*g, r in [0,8), g in [0,8).
//   r -> (jloc = r&1, gate = r>>1)  (PyTorch gate order i,f,g,o)
//   global gate row = gate*512 + 2*wg + jloc ; k-slice = [64g, 64g+64)
//   Each lane holds 64 fp32 of W_hh and 64 of W_ih in VGPRs.
//
// Cross-wave h exchange (R2-proven primitive): hbuf[2][512] of packed 8B
// words (hi32 = tag = t+1, lo32 = f32 h bits), posted with relaxed
// agent-scope atomic stores, polled with relaxed agent-scope atomic loads.
// Lane l polls words [8l, 8l+8) = one 64B line. No barriers anywhere in the
// loop: single-wave WG, LDS staging ordered by lockstep + lgkmcnt.

__global__ __launch_bounds__(WGSIZE, 1)
void lstm_wave(const float* __restrict__ x,      // [T,512]
               const float* __restrict__ Wih,    // [2048,512]
               const float* __restrict__ Whh,    // [2048,512]
               const float* __restrict__ bih,    // [2048]
               const float* __restrict__ bhh,    // [2048]
               float* __restrict__ out,          // [512]
               unsigned long long* hbuf)         // [2][512] tagged pairs
{
  const int wg   = blockIdx.x;
  const int lane = threadIdx.x;       // 0..63
  const int r    = lane & 7;
  const int g    = lane >> 3;
  const int k0   = g << 6;            // 64-float k-slice start
  const int jloc = r & 1;
  const int gate = r >> 1;            // 0=i 1=f 2=g 3=o
  const int hidx = wg * 2 + jloc;
  const int row  = gate * HID + hidx;

  __shared__ __align__(16) float hl[512];
  __shared__ __align__(16) float xl[512];

  // ---- load weights into registers (static indices only) ----
  float whh[64], wih[64];
#pragma unroll
  for (int i = 0; i < 16; ++i) {
    const int kk = k0 + (((i + g) & 15) << 2);
    float4 a = *reinterpret_cast<const float4*>(Whh + (size_t)row * 512 + kk);
    float4 b = *reinterpret_cast<const float4*>(Wih + (size_t)row * 512 + kk);
    whh[4*i+0] = a.x; whh[4*i+1] = a.y; whh[4*i+2] = a.z; whh[4*i+3] = a.w;
    wih[4*i+0] = b.x; wih[4*i+1] = b.y; wih[4*i+2] = b.z; wih[4*i+3] = b.w;
  }
  const float bias = bih[row] + bhh[row];

  // ---- stage x_0 (each lane owns x[8l..8l+8)) ----
  {
    const f4v* xp = reinterpret_cast<const f4v*>(x) + lane * 2;
    f4v a = xp[0], b = xp[1];
    *reinterpret_cast<f4v*>(&xl[lane * 8 + 0]) = a;
    *reinterpret_cast<f4v*>(&xl[lane * 8 + 4]) = b;
  }
  __builtin_amdgcn_wave_barrier();

  auto dot_lds = [&](const float* lds, const float* w) -> float {
    float acc = 0.f;
#pragma unroll
    for (int i = 0; i < 16; ++i) {
      const int kk = k0 + (((i + g) & 15) << 2);
      float4 v = *reinterpret_cast<const float4*>(lds + kk);
      acc = fmaf(w[4*i+0], v.x, acc);
      acc = fmaf(w[4*i+1], v.y, acc);
      acc = fmaf(w[4*i+2], v.z, acc);
      acc = fmaf(w[4*i+3], v.w, acc);
    }
    return acc;
  };

  float xacc = dot_lds(xl, wih);   // x-projection partial for t=0
  float c    = 0.f;

#pragma unroll 1
  for (int t = 0; t < T_STEPS; ++t) {
    // ---- prefetch x_{t+1} into registers (covered by ~1 step of latency) ----
    f4v xa, xb;
    const bool do_x = (t + 1 < T_STEPS);
    if (do_x) {
      const f4v* xp = reinterpret_cast<const f4v*>(x + (size_t)(t + 1) * 512) + lane * 2;
      xa = __builtin_nontemporal_load(xp);
      xb = __builtin_nontemporal_load(xp + 1);
    }

    // ---- poll h_{t-1}: lane l waits on its 64B line (8 tagged words) ----
    if (t > 0) {
      const unsigned long long* src = hbuf + (((t - 1) & 1) << 9) + lane * 8;
      const unsigned exp = (unsigned)t;
      unsigned long long p[8];
      bool ok;
      do {
#pragma unroll
        for (int j = 0; j < 8; ++j)
          p[j] = __hip_atomic_load(src + j, __ATOMIC_RELAXED, __HIP_MEMORY_SCOPE_AGENT);
        ok = true;
#pragma unroll
        for (int j = 0; j < 8; ++j) ok &= ((unsigned)(p[j] >> 32) == exp);
      } while (!__all(ok));

      f4v h0 = { __uint_as_float((unsigned)p[0]), __uint_as_float((unsigned)p[1]),
                 __uint_as_float((unsigned)p[2]), __uint_as_float((unsigned)p[3]) };
      f4v h1 = { __uint_as_float((unsigned)p[4]), __uint_as_float((unsigned)p[5]),
                 __uint_as_float((unsigned)p[6]), __uint_as_float((unsigned)p[7]) };
      *reinterpret_cast<f4v*>(&hl[lane * 8 + 0]) = h0;
      *reinterpret_cast<f4v*>(&hl[lane * 8 + 4]) = h1;
      __builtin_amdgcn_wave_barrier();   // keep stage->read order (lockstep wave)
    }

    // ---- gate pre-activation: xacc + h-dot, reduce over 8 k-groups ----
    float acc = xacc;
    if (t > 0) acc += dot_lds(hl, whh);
    acc += __shfl_xor(acc, 8);
    acc += __shfl_xor(acc, 16);
    acc += __shfl_xor(acc, 32);
    acc += bias;

    // ---- nonlinearity: sigmoid for i,f,o; tanh (=2*sig(2x)-1) for g ----
    const bool isg = (gate == 2);
    float xs = isg ? 2.f * acc : acc;
    float s  = 1.f / (1.f + expf(-xs));
    float v  = isg ? (2.f * s - 1.f) : s;

    // ---- gather i,f,g,o for my jloc via in-wave shuffles ----
    float iv = __shfl(v, jloc + 0);
    float fv = __shfl(v, jloc + 2);
    float gv = __shfl(v, jloc + 4);
    float ov = __shfl(v, jloc + 6);

    c = fv * c + iv * gv;
    float e2 = expf(-2.f * c);
    float th = 2.f / (1.f + e2) - 1.f;
    float hn = ov * th;

    // ---- post tagged h_t (lanes 0,1): fire-and-forget agent atomic ----
    if (lane < 2) {
      unsigned long long pk =
          ((unsigned long long)(unsigned)(t + 1) << 32) | (unsigned)__float_as_uint(hn);
      __hip_atomic_store(hbuf + ((t & 1) << 9) + wg * 2 + lane, pk,
                         __ATOMIC_RELAXED, __HIP_MEMORY_SCOPE_AGENT);
    }

    // ---- off critical path: stage x_{t+1}, fold x-projection for t+1 ----
    if (do_x) {
      *reinterpret_cast<f4v*>(&xl[lane * 8 + 0]) = xa;
      *reinterpret_cast<f4v*>(&xl[lane * 8 + 4]) = xb;
      __builtin_amdgcn_wave_barrier();
      xacc = dot_lds(xl, wih);
    }
  }

  // ---- softmax(h_{T-1}) by wg 0 (single wave) ----
  if (wg == 0) {
    const unsigned long long* src = hbuf + (((T_STEPS - 1) & 1) << 9) + lane * 8;
    unsigned long long p[8];
    bool ok;
    do {
#pragma unroll
      for (int j = 0; j < 8; ++j)
        p[j] = __hip_atomic_load(src + j, __ATOMIC_RELAXED, __HIP_MEMORY_SCOPE_AGENT);
      ok = true;
#pragma unroll
      for (int j = 0; j < 8; ++j) ok &= ((unsigned)(p[j] >> 32) == (unsigned)T_STEPS);
    } while (!__all(ok));

    float hv[8];
#pragma unroll
    for (int j = 0; j < 8; ++j) hv[j] = __uint_as_float((unsigned)p[j]);
    float mx = hv[0];
#pragma unroll
    for (int j = 1; j < 8; ++j) mx = fmaxf(mx, hv[j]);
    mx = fmaxf(mx, __shfl_xor(mx, 1));
    mx = fmaxf(mx, __shfl_xor(mx, 2));
    mx = fmaxf(mx, __shfl_xor(mx, 4));
    mx = fmaxf(mx, __shfl_xor(mx, 8));
    mx = fmaxf(mx, __shfl_xor(mx, 16));
    mx = fmaxf(mx, __shfl_xor(mx, 32));
    float ex[8], sum = 0.f;
#pragma unroll
    for (int j = 0; j < 8; ++j) { ex[j] = expf(hv[j] - mx); sum += ex[j]; }
    sum += __shfl_xor(sum, 1);
    sum += __shfl_xor(sum, 2);
    sum += __shfl_xor(sum, 4);
    sum += __shfl_xor(sum, 8);
    sum += __shfl_xor(sum, 16);
    sum += __shfl_xor(sum, 32);
    float inv = 1.f / sum;
#pragma unroll
    for (int j = 0; j < 8; ++j) out[lane * 8 + j] = ex[j] * inv;
  }
}

extern "C" void kernel_launch(void* const* d_in, const int* in_sizes, int n_in,
                              void* d_out, int out_size, void* d_ws, size_t ws_size,
                              hipStream_t stream) {
  const float* x   = (const float*)d_in[0];
  const float* Wih = (const float*)d_in[1];
  const float* Whh = (const float*)d_in[2];
  const float* bih = (const float*)d_in[3];
  const float* bhh = (const float*)d_in[4];
  float* out = (float*)d_out;
  unsigned long long* hbuf = (unsigned long long*)d_ws;   // 2*512*8B = 8 KB

  (void)hipMemsetAsync(d_ws, 0, 8192, stream);  // zero tags each launch (capture-safe)
  lstm_wave<<<NWG, WGSIZE, 0, stream>>>(x, Wih, Whh, bih, bhh, out, hbuf);
}